// Round 8
// baseline (121.528 us; speedup 1.0000x reference)
//
#include <hip/hip_runtime.h>
#include <math.h>

#define B_ 1024
#define D_ 2048
#define M_ 32
#define H_ 32

#define DPB 16        // d per block
#define DPW 4         // d per wave, sequential (wave-uniform d -> SGPR weights)
#define CB  64        // b per block = lanes per wave
#define OPAD 17       // out-gather pad

// Abramowitz & Stegun 7.1.26, |err| <= 1.5e-7 absolute. Uses hw rcp + exp.
__device__ __forceinline__ float fast_erff(float x) {
    float ax = fabsf(x);
    float t  = __builtin_amdgcn_rcpf(1.0f + 0.3275911f * ax);
    float p  = 1.061405429f;
    p = p * t - 1.453152027f;
    p = p * t + 1.421413741f;
    p = p * t - 0.284496736f;
    p = p * t + 0.254829592f;
    float e = __expf(-ax * ax);
    float r = 1.0f - p * t * e;
    return copysignf(r, x);
}

__device__ __forceinline__ float gelu_exact(float x) {
    return 0.5f * x * (1.0f + fast_erff(x * 0.70710678118f));
}

// tanh(x) = 1 - 2/(exp(2x)+1); exp(inf)->inf->rcp->0 gives +/-1 at extremes.
__device__ __forceinline__ float fast_tanhf(float x) {
    return 1.0f - 2.0f * __builtin_amdgcn_rcpf(__expf(2.0f * x) + 1.0f);
}

__global__ __launch_bounds__(256, 6)   // cap ~80 VGPR: room for rv[8] float4 to stay resident
void nlm_kernel(const float* __restrict__ pre,
                const float* __restrict__ w1,
                const float* __restrict__ b1,
                const float* __restrict__ w_out,
                const float* __restrict__ b_out,
                float* __restrict__ out) {
    __shared__ float obuf[CB * OPAD];   // 4.35 KB

    const int tid  = threadIdx.x;
    const int lane = tid & 63;
    const int w    = tid >> 6;                  // 0..3
    const int bx   = blockIdx.x;
    const int dt   = bx & (D_ / DPB - 1);       // 0..127: consecutive blocks walk d
    const int bt   = bx >> 7;                   // 0..15
    const int d0   = dt * DPB;
    const int b0   = bt * CB;
    const int b    = b0 + lane;

    // Wave-uniform d base -> SGPR weight addressing (s_load path).
    const int du = __builtin_amdgcn_readfirstlane(d0 + w * DPW);

    // All 32 row-loads (4 d x 8 float4) = one base + immediate offsets.
    const float* __restrict__ prow = pre + ((size_t)b * D_ + du) * M_;

#pragma unroll
    for (int i = 0; i < DPW; ++i) {
        // ---- load this d's pre row into registers (single buffer; TLP hides) ----
        float4 rv[8];
#pragma unroll
        for (int mg = 0; mg < 8; ++mg)
            rv[mg] = *reinterpret_cast<const float4*>(prow + i * M_ + mg * 4);

        const int dd = du + i;
        const float* __restrict__ wr  = w1    + (size_t)dd * (H_ * M_);
        const float* __restrict__ b1r = b1    + (size_t)dd * H_;
        const float* __restrict__ wor = w_out + (size_t)dd * H_;
        const float  bo = b_out[dd];

        float s = 0.f;
#pragma unroll 2
        for (int h = 0; h < H_; ++h) {
            float xe = b1r[h], xo = 0.f;
#pragma unroll
            for (int mg = 0; mg < 8; ++mg) {
                xe = fmaf(rv[mg].x, wr[h * M_ + mg * 4 + 0], xe);
                xo = fmaf(rv[mg].y, wr[h * M_ + mg * 4 + 1], xo);
                xe = fmaf(rv[mg].z, wr[h * M_ + mg * 4 + 2], xe);
                xo = fmaf(rv[mg].w, wr[h * M_ + mg * 4 + 3], xo);
            }
            s = fmaf(gelu_exact(xe + xo), wor[h], s);
        }
        obuf[lane * OPAD + (w * DPW + i)] = fast_tanhf(s + bo);
    }

    __syncthreads();

    // ---- flush: thread t -> row r=t>>2, 16-B chunk c=(t&3)*4; dwordx4 stores ----
    {
        const int r = tid >> 2;
        const int c = (tid & 3) * 4;
        float4 o;
        o.x = obuf[r * OPAD + c + 0];
        o.y = obuf[r * OPAD + c + 1];
        o.z = obuf[r * OPAD + c + 2];
        o.w = obuf[r * OPAD + c + 3];
        *reinterpret_cast<float4*>(out + (size_t)(b0 + r) * D_ + d0 + c) = o;
    }
}

extern "C" void kernel_launch(void* const* d_in, const int* in_sizes, int n_in,
                              void* d_out, int out_size, void* d_ws, size_t ws_size,
                              hipStream_t stream) {
    const float* pre   = (const float*)d_in[0];
    const float* w1    = (const float*)d_in[1];
    const float* b1    = (const float*)d_in[2];
    const float* w_out = (const float*)d_in[3];
    const float* b_out = (const float*)d_in[4];
    float* out = (float*)d_out;

    const int grid = (D_ / DPB) * (B_ / CB);   // 128 * 16 = 2048
    nlm_kernel<<<dim3(grid), dim3(256), 0, stream>>>(pre, w1, b1, w_out, b_out, out);
}

// Round 9
// 119.385 us; speedup vs baseline: 1.0179x; 1.0179x over previous
//
#include <hip/hip_runtime.h>
#include <math.h>

#define B_ 1024
#define D_ 2048
#define M_ 32
#define H_ 32

#define DPB 16        // d per block
#define DPW 4         // d per wave, sequential (wave-uniform d -> SGPR weights)
#define CB  64        // b per block = lanes per wave
#define OPAD 17       // out-gather pad

// Abramowitz & Stegun 7.1.26, |err| <= 1.5e-7 absolute. Uses hw rcp + exp.
__device__ __forceinline__ float fast_erff(float x) {
    float ax = fabsf(x);
    float t  = __builtin_amdgcn_rcpf(1.0f + 0.3275911f * ax);
    float p  = 1.061405429f;
    p = p * t - 1.453152027f;
    p = p * t + 1.421413741f;
    p = p * t - 0.284496736f;
    p = p * t + 0.254829592f;
    float e = __expf(-ax * ax);
    float r = 1.0f - p * t * e;
    return copysignf(r, x);
}

__device__ __forceinline__ float gelu_exact(float x) {
    return 0.5f * x * (1.0f + fast_erff(x * 0.70710678118f));
}

// tanh(x) = 1 - 2/(exp(2x)+1); exp(inf)->inf->rcp->0 gives +/-1 at extremes.
__device__ __forceinline__ float fast_tanhf(float x) {
    return 1.0f - 2.0f * __builtin_amdgcn_rcpf(__expf(2.0f * x) + 1.0f);
}

__global__ __launch_bounds__(256)
void nlm_kernel(const float* __restrict__ pre,
                const float* __restrict__ w1,
                const float* __restrict__ b1,
                const float* __restrict__ w_out,
                const float* __restrict__ b_out,
                float* __restrict__ out) {
    __shared__ float obuf[CB * OPAD];   // 4.35 KB

    const int tid  = threadIdx.x;
    const int lane = tid & 63;
    const int w    = tid >> 6;                  // 0..3
    const int bx   = blockIdx.x;
    const int dt   = bx & (D_ / DPB - 1);       // 0..127: consecutive blocks walk d
    const int bt   = bx >> 7;                   // 0..15
    const int d0   = dt * DPB;
    const int b0   = bt * CB;
    const int b    = b0 + lane;

    // Wave-uniform d base -> SGPR weight addressing (s_load path).
    const int du = __builtin_amdgcn_readfirstlane(d0 + w * DPW);
    const float* __restrict__ prow = pre + ((size_t)b * D_ + du) * M_;

#pragma unroll 1   // keep the d-loop ROLLED: per-d body is ~13 KB of unrolled code
    for (int i = 0; i < DPW; ++i) {
        const int dd = du + i;
        const float* __restrict__ wr  = w1    + (size_t)dd * (H_ * M_);
        const float* __restrict__ b1r = b1    + (size_t)dd * H_;
        const float* __restrict__ wor = w_out + (size_t)dd * H_;

        // ---- load pre row (8 float4), then PIN: asm output is opaque ->
        // compiler cannot rematerialize these loads inside the loops below.
        float4 rv[8];
#pragma unroll
        for (int mg = 0; mg < 8; ++mg)
            rv[mg] = *reinterpret_cast<const float4*>(prow + i * M_ + mg * 4);
#pragma unroll
        for (int mg = 0; mg < 8; ++mg)
            asm volatile("" : "+v"(rv[mg].x), "+v"(rv[mg].y),
                              "+v"(rv[mg].z), "+v"(rv[mg].w));

        // ---- accumulator form: acc[h] is COMPUTED state (cannot be re-loaded);
        // each rv[mg] is consumed immediately by its 32 FMA4s.
        float acc[H_];
#pragma unroll
        for (int h = 0; h < H_; ++h) acc[h] = b1r[h];

#pragma unroll
        for (int mg = 0; mg < 8; ++mg) {
#pragma unroll
            for (int h = 0; h < H_; ++h) {
                acc[h] = fmaf(rv[mg].x, wr[h * M_ + mg * 4 + 0], acc[h]);
                acc[h] = fmaf(rv[mg].y, wr[h * M_ + mg * 4 + 1], acc[h]);
                acc[h] = fmaf(rv[mg].z, wr[h * M_ + mg * 4 + 2], acc[h]);
                acc[h] = fmaf(rv[mg].w, wr[h * M_ + mg * 4 + 3], acc[h]);
            }
        }

        // ---- epilogue: GELU + output dot + tanh ----
        float s = 0.f;
#pragma unroll
        for (int h = 0; h < H_; ++h)
            s = fmaf(gelu_exact(acc[h]), wor[h], s);

        obuf[lane * OPAD + (w * DPW + i)] = fast_tanhf(s + b_out[dd]);
    }

    __syncthreads();

    // ---- flush: thread t -> row r=t>>2, 16-B chunk c=(t&3)*4; dwordx4 stores ----
    {
        const int r = tid >> 2;
        const int c = (tid & 3) * 4;
        float4 o;
        o.x = obuf[r * OPAD + c + 0];
        o.y = obuf[r * OPAD + c + 1];
        o.z = obuf[r * OPAD + c + 2];
        o.w = obuf[r * OPAD + c + 3];
        *reinterpret_cast<float4*>(out + (size_t)(b0 + r) * D_ + d0 + c) = o;
    }
}

extern "C" void kernel_launch(void* const* d_in, const int* in_sizes, int n_in,
                              void* d_out, int out_size, void* d_ws, size_t ws_size,
                              hipStream_t stream) {
    const float* pre   = (const float*)d_in[0];
    const float* w1    = (const float*)d_in[1];
    const float* b1    = (const float*)d_in[2];
    const float* w_out = (const float*)d_in[3];
    const float* b_out = (const float*)d_in[4];
    float* out = (float*)d_out;

    const int grid = (D_ / DPB) * (B_ / CB);   // 128 * 16 = 2048
    nlm_kernel<<<dim3(grid), dim3(256), 0, stream>>>(pre, w1, b1, w_out, b_out, out);
}